// Round 1
// baseline (261.017 us; speedup 1.0000x reference)
//
#include <hip/hip_runtime.h>
#include <hip/hip_bf16.h>

// Pipeline:
//  k_wconv : qkv_w/proj_w fp32 -> bf16 (q rows pre-scaled by temperature[h]/8)
//  k_pool  : x (512,256,256) -> pooled xp (512,64,64) fp32 + per-group partial sum/sumsq
//  k_stats : deterministic reduce partials -> mean/rstd per group (8)
//  k_xr    : xr = GN_affine(xp) + posenc -> bf16 (512,4096)
//  k_gemm  : qkv = Wq(1536,512) x xr(512,4096) -> bf16
//  k_attn  : flash attention per (head, 64-n tile), swapped-QK^T online softmax
//  k_gemm  : low = Wp(512,512) x attn(512,4096) -> bf16   [proj commuted below upsample]
//  k_up    : out = x + gamma * (bilerp_4x(low) + proj_b)

typedef __attribute__((ext_vector_type(4))) short short4v;
typedef __attribute__((ext_vector_type(8))) short short8v;
typedef __attribute__((ext_vector_type(4))) float f32x4;

#define MFMA16(a, b, c) __builtin_amdgcn_mfma_f32_16x16x32_bf16(a, b, c, 0, 0, 0)

__device__ __forceinline__ unsigned short bf16r(float f) {
    unsigned int u = __builtin_bit_cast(unsigned int, f);
    u += 0x7fffu + ((u >> 16) & 1u);
    return (unsigned short)(u >> 16);
}
__device__ __forceinline__ float bff(unsigned short s) {
    unsigned int u = ((unsigned int)s) << 16;
    return __builtin_bit_cast(float, u);
}

// ---------------- weight conversion (+ q scaling folded into Wq) ----------------
__global__ __launch_bounds__(256) void k_wconv(const float* __restrict__ qkv_w,
                                               const float* __restrict__ proj_w,
                                               const float* __restrict__ temp,
                                               unsigned short* __restrict__ wq_b,
                                               unsigned short* __restrict__ wp_b) {
    int idx = blockIdx.x * 256 + threadIdx.x;  // 0 .. 1536*512 + 512*512 - 1
    const int NQ = 1536 * 512;
    if (idx < NQ) {
        int o = idx >> 9;
        float sc = (o < 512) ? temp[o >> 6] * 0.125f : 1.0f;  // hd^-0.5 = 1/8
        wq_b[idx] = bf16r(qkv_w[idx] * sc);
    } else {
        int j = idx - NQ;
        wp_b[j] = bf16r(proj_w[j]);
    }
}

// ---------------- pool + group partial stats ----------------
__global__ __launch_bounds__(256) void k_pool(const float* __restrict__ x,
                                              float* __restrict__ xp,
                                              float* __restrict__ partials) {
    int hr = blockIdx.x;   // 0..63
    int c  = blockIdx.y;   // 0..511
    int t = threadIdx.x;
    int r = t >> 6, wq = t & 63;
    const float4* src = (const float4*)(x + (size_t)c * 65536 + (size_t)(4 * hr + r) * 256 + 4 * wq);
    float4 v = *src;
    float s4 = v.x + v.y + v.z + v.w;
    float q4 = v.x * v.x + v.y * v.y + v.z * v.z + v.w * v.w;

    __shared__ float sm[256];
    __shared__ float wq4[4];
    sm[t] = s4;
    float qq = q4;
#pragma unroll
    for (int off = 1; off < 64; off <<= 1) qq += __shfl_xor(qq, off, 64);
    if ((t & 63) == 0) wq4[t >> 6] = qq;
    __syncthreads();
    if (t < 64) {
        float cs = sm[t] + sm[64 + t] + sm[128 + t] + sm[192 + t];
        xp[(size_t)c * 4096 + hr * 64 + t] = cs * (1.0f / 16.0f);
        float ts = cs;
#pragma unroll
        for (int off = 1; off < 64; off <<= 1) ts += __shfl_xor(ts, off, 64);
        if (t == 0) {
            int g = c >> 6;
            int slot = (c & 63) * 64 + hr;
            partials[(size_t)(g * 4096 + slot) * 2 + 0] = ts;
            partials[(size_t)(g * 4096 + slot) * 2 + 1] = wq4[0] + wq4[1] + wq4[2] + wq4[3];
        }
    }
}

// ---------------- group stats finalize ----------------
__global__ __launch_bounds__(256) void k_stats(const float* __restrict__ partials,
                                               float* __restrict__ gstats) {
    int g = blockIdx.x;
    int t = threadIdx.x;
    float s = 0.f, q = 0.f;
    for (int i = t; i < 4096; i += 256) {
        s += partials[(size_t)(g * 4096 + i) * 2 + 0];
        q += partials[(size_t)(g * 4096 + i) * 2 + 1];
    }
#pragma unroll
    for (int off = 1; off < 64; off <<= 1) {
        s += __shfl_xor(s, off, 64);
        q += __shfl_xor(q, off, 64);
    }
    __shared__ float ss[4], qs[4];
    if ((t & 63) == 0) { ss[t >> 6] = s; qs[t >> 6] = q; }
    __syncthreads();
    if (t == 0) {
        float S = ss[0] + ss[1] + ss[2] + ss[3];
        float Q = qs[0] + qs[1] + qs[2] + qs[3];
        const float inv = 1.0f / 4194304.0f;  // 64 ch * 65536 px
        float m = S * inv;
        float var = Q * inv - m * m;
        gstats[2 * g] = m;
        gstats[2 * g + 1] = rsqrtf(var + 1e-5f);
    }
}

// ---------------- GN affine + positional encoding -> bf16 ----------------
__global__ __launch_bounds__(256) void k_xr(const float* __restrict__ xp,
                                            const float* __restrict__ gs,
                                            const float* __restrict__ gw,
                                            const float* __restrict__ gb,
                                            unsigned short* __restrict__ xr) {
    int idx = blockIdx.x * 256 + threadIdx.x;  // 512*4096
    int c = idx >> 12, n = idx & 4095;
    int hr = n >> 6, wr = n & 63;
    int g = c >> 6;
    float m = gs[2 * g], rs = gs[2 * g + 1];
    float xn = (xp[idx] - m) * rs * gw[c] + gb[c];
    int i = c >> 2, kind = c & 3;
    float di = expf(-(float)i * 0.07195578415606394f);  // ln(1e4)/128
    float arg = ((kind < 2) ? (float)hr : (float)wr) * di;
    float pe = 0.01f * ((kind & 1) ? cosf(arg) : sinf(arg));
    xr[idx] = bf16r(xn + pe);
}

// ---------------- bf16 GEMM: C[M,4096] = A[M,512] * B[512,4096] ----------------
__global__ __launch_bounds__(256) void k_gemm(const unsigned short* __restrict__ A,
                                              const unsigned short* __restrict__ B,
                                              unsigned short* __restrict__ C) {
    __shared__ unsigned short As[128][36];   // [m][k], padded
    __shared__ unsigned short Bs[128][36];   // [n][k] (transposed), padded
    int t = threadIdx.x;
    int w = t >> 6, l = t & 63, l15 = l & 15, lg = l >> 4;
    int wrow = w >> 1, wcol = w & 1;
    int m0 = blockIdx.y * 128, n0 = blockIdx.x * 128;
    f32x4 acc[4][4] = {};

    for (int k0 = 0; k0 < 512; k0 += 32) {
#pragma unroll
        for (int i = 0; i < 4; i++) {  // A tile 128x32
            int idx = t + 256 * i;
            int row = idx >> 3, kc = idx & 7;
            short4v av = *(const short4v*)(A + (size_t)(m0 + row) * 512 + k0 + 4 * kc);
            *(short4v*)&As[row][4 * kc] = av;
        }
#pragma unroll
        for (int i = 0; i < 4; i++) {  // B tile 32x128 -> transposed
            int idx = t + 256 * i;
            int kr = idx >> 5, nc = idx & 31;
            short4v bv = *(const short4v*)(B + (size_t)(k0 + kr) * 4096 + n0 + 4 * nc);
#pragma unroll
            for (int j = 0; j < 4; j++) Bs[4 * nc + j][kr] = (unsigned short)bv[j];
        }
        __syncthreads();

        short8v af[4];
#pragma unroll
        for (int mi = 0; mi < 4; mi++) {
            int ar = wrow * 64 + mi * 16 + l15;
            short4v a0 = *(const short4v*)&As[ar][4 * lg];
            short4v a1 = *(const short4v*)&As[ar][16 + 4 * lg];
            af[mi] = __builtin_shufflevector(a0, a1, 0, 1, 2, 3, 4, 5, 6, 7);
        }
#pragma unroll
        for (int ni = 0; ni < 4; ni++) {
            int bc = wcol * 64 + ni * 16 + l15;
            short4v b0 = *(const short4v*)&Bs[bc][4 * lg];
            short4v b1 = *(const short4v*)&Bs[bc][16 + 4 * lg];
            short8v bf = __builtin_shufflevector(b0, b1, 0, 1, 2, 3, 4, 5, 6, 7);
#pragma unroll
            for (int mi = 0; mi < 4; mi++) acc[mi][ni] = MFMA16(af[mi], bf, acc[mi][ni]);
        }
        __syncthreads();
    }
#pragma unroll
    for (int mi = 0; mi < 4; mi++)
#pragma unroll
        for (int ni = 0; ni < 4; ni++) {
            int row = m0 + wrow * 64 + mi * 16 + 4 * lg;
            int col = n0 + wcol * 64 + ni * 16 + l15;
#pragma unroll
            for (int r = 0; r < 4; r++)
                C[(size_t)(row + r) * 4096 + col] = bf16r(acc[mi][ni][r]);
        }
}

// ---------------- flash attention (swapped QK^T, online softmax) ----------------
__global__ __launch_bounds__(256) void k_attn(const unsigned short* __restrict__ qkv,
                                              unsigned short* __restrict__ outb) {
    __shared__ unsigned short Kt[64][68];  // [m][d]
    __shared__ unsigned short Vl[64][68];  // [d][m]
    int t = threadIdx.x;
    int w = t >> 6, l = t & 63, l15 = l & 15, lg = l >> 4;
    int h = blockIdx.y, qt = blockIdx.x;
    int n = qt * 64 + w * 16 + l15;

    const unsigned short* qb = qkv + (size_t)(h * 64) * 4096;
    const unsigned short* kb = qkv + (size_t)(512 + h * 64) * 4096;
    const unsigned short* vb = qkv + (size_t)(1024 + h * 64) * 4096;

    // Q fragments (B-operand): qf[s][j] = q[d][n], d per MFMA k-map
    short8v qf[2];
#pragma unroll
    for (int s = 0; s < 2; s++) {
        short8v v;
#pragma unroll
        for (int j = 0; j < 8; j++) {
            int d = s * 32 + ((j < 4) ? (4 * lg + j) : (16 + 4 * lg + (j - 4)));
            v[j] = (short)qb[(size_t)d * 4096 + n];
        }
        qf[s] = v;
    }

    f32x4 od[4] = {};
    float mrun = -INFINITY, lrun = 0.f;

    for (int kt = 0; kt < 64; kt++) {
        int m0 = kt * 64;
#pragma unroll
        for (int i = 0; i < 4; i++) {  // stage K (transposed) and V
            int idx = t + 256 * i;
            int d = idx >> 4, mc = idx & 15;
            short4v kv = *(const short4v*)(kb + (size_t)d * 4096 + m0 + 4 * mc);
#pragma unroll
            for (int j = 0; j < 4; j++) Kt[4 * mc + j][d] = (unsigned short)kv[j];
            short4v vv = *(const short4v*)(vb + (size_t)d * 4096 + m0 + 4 * mc);
            *(short4v*)&Vl[d][4 * mc] = vv;
        }
        __syncthreads();

        // S^T[m][n] = sum_d K^T[m][d] q[d][n]
        f32x4 st[4];
#pragma unroll
        for (int mf = 0; mf < 4; mf++) {
            int mrow = 16 * mf + l15;
            short4v a0 = *(const short4v*)&Kt[mrow][4 * lg];
            short4v a1 = *(const short4v*)&Kt[mrow][16 + 4 * lg];
            short4v a2 = *(const short4v*)&Kt[mrow][32 + 4 * lg];
            short4v a3 = *(const short4v*)&Kt[mrow][48 + 4 * lg];
            short8v A0 = __builtin_shufflevector(a0, a1, 0, 1, 2, 3, 4, 5, 6, 7);
            short8v A1 = __builtin_shufflevector(a2, a3, 0, 1, 2, 3, 4, 5, 6, 7);
            f32x4 z = {};
            z = MFMA16(A0, qf[0], z);
            z = MFMA16(A1, qf[1], z);
            st[mf] = z;
        }

        // online softmax over m (rows of S^T): lane-local 16 + xor16 + xor32
        float pm = -INFINITY;
#pragma unroll
        for (int mf = 0; mf < 4; mf++)
#pragma unroll
            for (int r = 0; r < 4; r++) pm = fmaxf(pm, st[mf][r]);
        pm = fmaxf(pm, __shfl_xor(pm, 16, 64));
        pm = fmaxf(pm, __shfl_xor(pm, 32, 64));
        float mnew = fmaxf(mrun, pm);
        float alpha = __expf(mrun - mnew);
        float p[4][4];
        float ps = 0.f;
#pragma unroll
        for (int mf = 0; mf < 4; mf++)
#pragma unroll
            for (int r = 0; r < 4; r++) {
                float e = __expf(st[mf][r] - mnew);
                p[mf][r] = e;
                ps += e;
            }
        ps += __shfl_xor(ps, 16, 64);
        ps += __shfl_xor(ps, 32, 64);
        lrun = lrun * alpha + ps;
        mrun = mnew;
#pragma unroll
        for (int dg = 0; dg < 4; dg++)
#pragma unroll
            for (int r = 0; r < 4; r++) od[dg][r] *= alpha;

        // pack P^T -> bf16 B-operand fragments (layout-exact hand-off)
        short8v pb0, pb1;
#pragma unroll
        for (int j = 0; j < 8; j++) {
            pb0[j] = (short)bf16r(p[(j >> 2)][j & 3]);
            pb1[j] = (short)bf16r(p[2 + (j >> 2)][j & 3]);
        }

        // O^T[d][n] += V[d][m] * P^T[m][n]
#pragma unroll
        for (int dg = 0; dg < 4; dg++) {
            int drow = 16 * dg + l15;
            short4v a0 = *(const short4v*)&Vl[drow][4 * lg];
            short4v a1 = *(const short4v*)&Vl[drow][16 + 4 * lg];
            short4v a2 = *(const short4v*)&Vl[drow][32 + 4 * lg];
            short4v a3 = *(const short4v*)&Vl[drow][48 + 4 * lg];
            short8v A0 = __builtin_shufflevector(a0, a1, 0, 1, 2, 3, 4, 5, 6, 7);
            short8v A1 = __builtin_shufflevector(a2, a3, 0, 1, 2, 3, 4, 5, 6, 7);
            od[dg] = MFMA16(A0, pb0, od[dg]);
            od[dg] = MFMA16(A1, pb1, od[dg]);
        }
        __syncthreads();
    }

    float inv = 1.0f / lrun;
#pragma unroll
    for (int dg = 0; dg < 4; dg++)
#pragma unroll
        for (int r = 0; r < 4; r++) {
            int d = 16 * dg + 4 * lg + r;
            outb[(size_t)(h * 64 + d) * 4096 + n] = bf16r(od[dg][r] * inv);
        }
}

// ---------------- bilinear upsample 64->256 + bias + residual ----------------
__global__ __launch_bounds__(256) void k_up(const float* __restrict__ x,
                                            const unsigned short* __restrict__ low,
                                            const float* __restrict__ proj_b,
                                            const float* __restrict__ gamma,
                                            float* __restrict__ out) {
    int hh = blockIdx.x, c = blockIdx.y, ww = threadIdx.x;
    int Ah = hh >> 2, ph = hh & 3;
    int y0 = Ah + ((ph < 2) ? -1 : 0);
    float fy = (ph < 2) ? (0.625f + 0.25f * ph) : (0.125f + 0.25f * (ph - 2));
    int y1 = min(y0 + 1, 63); y0 = max(y0, 0);
    int Aw = ww >> 2, pw = ww & 3;
    int x0 = Aw + ((pw < 2) ? -1 : 0);
    float fx = (pw < 2) ? (0.625f + 0.25f * pw) : (0.125f + 0.25f * (pw - 2));
    int x1 = min(x0 + 1, 63); x0 = max(x0, 0);

    const unsigned short* L = low + (size_t)c * 4096;
    float v00 = bff(L[y0 * 64 + x0]), v01 = bff(L[y0 * 64 + x1]);
    float v10 = bff(L[y1 * 64 + x0]), v11 = bff(L[y1 * 64 + x1]);
    float val = (1.f - fy) * ((1.f - fx) * v00 + fx * v01) + fy * ((1.f - fx) * v10 + fx * v11);
    size_t idx = (size_t)c * 65536 + (size_t)hh * 256 + ww;
    out[idx] = x[idx] + gamma[0] * (val + proj_b[c]);
}

extern "C" void kernel_launch(void* const* d_in, const int* in_sizes, int n_in,
                              void* d_out, int out_size, void* d_ws, size_t ws_size,
                              hipStream_t stream) {
    const float* x     = (const float*)d_in[0];
    const float* gnw   = (const float*)d_in[1];
    const float* gnb   = (const float*)d_in[2];
    const float* qkvw  = (const float*)d_in[3];
    const float* projw = (const float*)d_in[4];
    const float* projb = (const float*)d_in[5];
    const float* gamma = (const float*)d_in[6];
    const float* temp  = (const float*)d_in[7];

    char* ws = (char*)d_ws;
    const size_t MB = 1u << 20;
    float* gstats          = (float*)(ws + 0);
    float* partials        = (float*)(ws + 1024);
    float* xp              = (float*)(ws + 1 * MB);
    unsigned short* xr_b   = (unsigned short*)(ws + 9 * MB);
    unsigned short* wq_b   = (unsigned short*)(ws + 13 * MB);
    unsigned short* wp_b   = (unsigned short*)(ws + 15 * MB);
    unsigned short* qkv_b  = (unsigned short*)(ws + 16 * MB);
    unsigned short* attn_b = (unsigned short*)(ws + 28 * MB);
    unsigned short* low_b  = (unsigned short*)(ws + 32 * MB);
    float* out = (float*)d_out;

    k_wconv<<<4096, 256, 0, stream>>>(qkvw, projw, temp, wq_b, wp_b);
    k_pool<<<dim3(64, 512), 256, 0, stream>>>(x, xp, partials);
    k_stats<<<8, 256, 0, stream>>>(partials, gstats);
    k_xr<<<8192, 256, 0, stream>>>(xp, gstats, gnw, gnb, xr_b);
    k_gemm<<<dim3(32, 12), 256, 0, stream>>>(wq_b, xr_b, qkv_b);
    k_attn<<<dim3(64, 8), 256, 0, stream>>>(qkv_b, attn_b);
    k_gemm<<<dim3(32, 4), 256, 0, stream>>>(wp_b, attn_b, low_b);
    k_up<<<dim3(256, 512), 256, 0, stream>>>(x, low_b, projb, gamma, out);
}

// Round 2
// 231.196 us; speedup vs baseline: 1.1290x; 1.1290x over previous
//
#include <hip/hip_runtime.h>
#include <hip/hip_bf16.h>

// Pipeline:
//  k_wconv : qkv_w/proj_w fp32 -> bf16 (q rows pre-scaled by temperature[h]/8)
//  k_pool  : x (512,256,256) -> pooled xp (512,64,64) fp32 + per-group partial sum/sumsq
//  k_stats : reduce partials -> mean/rstd per group
//  k_xr    : xr = GN_affine(xp) + posenc -> bf16 (512,4096)
//  k_gemm  : qkv = Wq(1536,512) x xr(512,4096) -> bf16
//  k_ktr   : K section (512,4096) -> ktg (8,4096,64)  [so attn can async-stage K]
//  k_attn  : flash attn, swapped QK^T, gl_lds staging + XOR swizzle + defer-max
//  k_gemm  : low = Wp(512,512) x attn(512,4096) -> bf16
//  k_up    : out = x + gamma * (bilerp_4x(low) + proj_b)   [float4 vectorized]

typedef __attribute__((ext_vector_type(4))) short short4v;
typedef __attribute__((ext_vector_type(8))) short short8v;
typedef __attribute__((ext_vector_type(4))) float f32x4;
typedef __attribute__((ext_vector_type(4))) unsigned int u32x4;

#define MFMA16(a, b, c) __builtin_amdgcn_mfma_f32_16x16x32_bf16(a, b, c, 0, 0, 0)

__device__ __forceinline__ unsigned short bf16r(float f) {
    unsigned int u = __builtin_bit_cast(unsigned int, f);
    u += 0x7fffu + ((u >> 16) & 1u);
    return (unsigned short)(u >> 16);
}
__device__ __forceinline__ float bff(unsigned short s) {
    unsigned int u = ((unsigned int)s) << 16;
    return __builtin_bit_cast(float, u);
}

typedef const __attribute__((address_space(1))) unsigned int guint;
typedef __attribute__((address_space(3))) unsigned int luint;
__device__ __forceinline__ void gload16(const void* g, void* l) {
    __builtin_amdgcn_global_load_lds((guint*)g, (luint*)l, 16, 0, 0);
}

// ---------------- weight conversion ----------------
__global__ __launch_bounds__(256) void k_wconv(const float* __restrict__ qkv_w,
                                               const float* __restrict__ proj_w,
                                               const float* __restrict__ temp,
                                               unsigned short* __restrict__ wq_b,
                                               unsigned short* __restrict__ wp_b) {
    int idx = blockIdx.x * 256 + threadIdx.x;
    const int NQ = 1536 * 512;
    if (idx < NQ) {
        int o = idx >> 9;
        float sc = (o < 512) ? temp[o >> 6] * 0.125f : 1.0f;
        wq_b[idx] = bf16r(qkv_w[idx] * sc);
    } else {
        int j = idx - NQ;
        wp_b[j] = bf16r(proj_w[j]);
    }
}

// ---------------- pool + group partial stats ----------------
__global__ __launch_bounds__(256) void k_pool(const float* __restrict__ x,
                                              float* __restrict__ xp,
                                              float* __restrict__ partials) {
    int hr = blockIdx.x;
    int c  = blockIdx.y;
    int t = threadIdx.x;
    int r = t >> 6, wq = t & 63;
    const float4* src = (const float4*)(x + (size_t)c * 65536 + (size_t)(4 * hr + r) * 256 + 4 * wq);
    float4 v = *src;
    float s4 = v.x + v.y + v.z + v.w;
    float q4 = v.x * v.x + v.y * v.y + v.z * v.z + v.w * v.w;

    __shared__ float sm[256];
    __shared__ float wq4[4];
    sm[t] = s4;
    float qq = q4;
#pragma unroll
    for (int off = 1; off < 64; off <<= 1) qq += __shfl_xor(qq, off, 64);
    if ((t & 63) == 0) wq4[t >> 6] = qq;
    __syncthreads();
    if (t < 64) {
        float cs = sm[t] + sm[64 + t] + sm[128 + t] + sm[192 + t];
        xp[(size_t)c * 4096 + hr * 64 + t] = cs * (1.0f / 16.0f);
        float ts = cs;
#pragma unroll
        for (int off = 1; off < 64; off <<= 1) ts += __shfl_xor(ts, off, 64);
        if (t == 0) {
            int g = c >> 6;
            int slot = (c & 63) * 64 + hr;
            partials[(size_t)(g * 4096 + slot) * 2 + 0] = ts;
            partials[(size_t)(g * 4096 + slot) * 2 + 1] = wq4[0] + wq4[1] + wq4[2] + wq4[3];
        }
    }
}

// ---------------- group stats finalize ----------------
__global__ __launch_bounds__(256) void k_stats(const float* __restrict__ partials,
                                               float* __restrict__ gstats) {
    int g = blockIdx.x;
    int t = threadIdx.x;
    float s = 0.f, q = 0.f;
    for (int i = t; i < 4096; i += 256) {
        s += partials[(size_t)(g * 4096 + i) * 2 + 0];
        q += partials[(size_t)(g * 4096 + i) * 2 + 1];
    }
#pragma unroll
    for (int off = 1; off < 64; off <<= 1) {
        s += __shfl_xor(s, off, 64);
        q += __shfl_xor(q, off, 64);
    }
    __shared__ float ss[4], qs[4];
    if ((t & 63) == 0) { ss[t >> 6] = s; qs[t >> 6] = q; }
    __syncthreads();
    if (t == 0) {
        float S = ss[0] + ss[1] + ss[2] + ss[3];
        float Q = qs[0] + qs[1] + qs[2] + qs[3];
        const float inv = 1.0f / 4194304.0f;
        float m = S * inv;
        float var = Q * inv - m * m;
        gstats[2 * g] = m;
        gstats[2 * g + 1] = rsqrtf(var + 1e-5f);
    }
}

// ---------------- GN affine + positional encoding -> bf16 ----------------
__global__ __launch_bounds__(256) void k_xr(const float* __restrict__ xp,
                                            const float* __restrict__ gs,
                                            const float* __restrict__ gw,
                                            const float* __restrict__ gb,
                                            unsigned short* __restrict__ xr) {
    int idx = blockIdx.x * 256 + threadIdx.x;
    int c = idx >> 12, n = idx & 4095;
    int hr = n >> 6, wr = n & 63;
    int g = c >> 6;
    float m = gs[2 * g], rs = gs[2 * g + 1];
    float xn = (xp[idx] - m) * rs * gw[c] + gb[c];
    int i = c >> 2, kind = c & 3;
    float di = expf(-(float)i * 0.07195578415606394f);
    float arg = ((kind < 2) ? (float)hr : (float)wr) * di;
    float pe = 0.01f * ((kind & 1) ? cosf(arg) : sinf(arg));
    xr[idx] = bf16r(xn + pe);
}

// ---------------- bf16 GEMM: C[M,4096] = A[M,512] * B[512,4096] ----------------
__global__ __launch_bounds__(256) void k_gemm(const unsigned short* __restrict__ A,
                                              const unsigned short* __restrict__ B,
                                              unsigned short* __restrict__ C) {
    __shared__ unsigned short As[128][36];
    __shared__ unsigned short Bs[128][36];
    int t = threadIdx.x;
    int w = t >> 6, l = t & 63, l15 = l & 15, lg = l >> 4;
    int wrow = w >> 1, wcol = w & 1;
    int m0 = blockIdx.y * 128, n0 = blockIdx.x * 128;
    f32x4 acc[4][4] = {};

    for (int k0 = 0; k0 < 512; k0 += 32) {
#pragma unroll
        for (int i = 0; i < 4; i++) {
            int idx = t + 256 * i;
            int row = idx >> 3, kc = idx & 7;
            short4v av = *(const short4v*)(A + (size_t)(m0 + row) * 512 + k0 + 4 * kc);
            *(short4v*)&As[row][4 * kc] = av;
        }
#pragma unroll
        for (int i = 0; i < 4; i++) {
            int idx = t + 256 * i;
            int kr = idx >> 5, nc = idx & 31;
            short4v bv = *(const short4v*)(B + (size_t)(k0 + kr) * 4096 + n0 + 4 * nc);
#pragma unroll
            for (int j = 0; j < 4; j++) Bs[4 * nc + j][kr] = (unsigned short)bv[j];
        }
        __syncthreads();

        short8v af[4];
#pragma unroll
        for (int mi = 0; mi < 4; mi++) {
            int ar = wrow * 64 + mi * 16 + l15;
            short4v a0 = *(const short4v*)&As[ar][4 * lg];
            short4v a1 = *(const short4v*)&As[ar][16 + 4 * lg];
            af[mi] = __builtin_shufflevector(a0, a1, 0, 1, 2, 3, 4, 5, 6, 7);
        }
#pragma unroll
        for (int ni = 0; ni < 4; ni++) {
            int bc = wcol * 64 + ni * 16 + l15;
            short4v b0 = *(const short4v*)&Bs[bc][4 * lg];
            short4v b1 = *(const short4v*)&Bs[bc][16 + 4 * lg];
            short8v bf = __builtin_shufflevector(b0, b1, 0, 1, 2, 3, 4, 5, 6, 7);
#pragma unroll
            for (int mi = 0; mi < 4; mi++) acc[mi][ni] = MFMA16(af[mi], bf, acc[mi][ni]);
        }
        __syncthreads();
    }
#pragma unroll
    for (int mi = 0; mi < 4; mi++)
#pragma unroll
        for (int ni = 0; ni < 4; ni++) {
            int row = m0 + wrow * 64 + mi * 16 + 4 * lg;
            int col = n0 + wcol * 64 + ni * 16 + l15;
#pragma unroll
            for (int r = 0; r < 4; r++)
                C[(size_t)(row + r) * 4096 + col] = bf16r(acc[mi][ni][r]);
        }
}

// ---------------- K transpose: qkv K section -> ktg[h][m][d] ----------------
__global__ __launch_bounds__(256) void k_ktr(const unsigned short* __restrict__ qkv,
                                             unsigned short* __restrict__ ktg) {
    __shared__ unsigned short lt[64][72];
    int t = threadIdx.x;
    int mt = blockIdx.x;   // 0..63
    int h  = blockIdx.y;   // 0..7
    const unsigned short* kb = qkv + (size_t)(512 + h * 64) * 4096 + mt * 64;
    int d = t >> 2, seg = t & 3;
    short8v v0 = *(const short8v*)(kb + (size_t)d * 4096 + seg * 16);
    short8v v1 = *(const short8v*)(kb + (size_t)d * 4096 + seg * 16 + 8);
    *(short8v*)&lt[d][seg * 16] = v0;
    *(short8v*)&lt[d][seg * 16 + 8] = v1;
    __syncthreads();
    int m = t >> 2, ds = t & 3;
    unsigned short o[16];
#pragma unroll
    for (int j = 0; j < 16; j++) o[j] = lt[ds * 16 + j][m];
    unsigned short* dst = ktg + ((size_t)h * 4096 + (size_t)mt * 64 + m) * 64 + ds * 16;
    *(short8v*)dst = *(const short8v*)&o[0];
    *(short8v*)(dst + 8) = *(const short8v*)&o[8];
}

// ---------------- flash attention ----------------
// K tile in LDS: [m][d] rows of 128B, 16B-chunk XOR-swizzled: chunk' = chunk ^ (m&7)
// V tile in LDS: [d][m] rows of 128B, chunk' = chunk ^ (d&7)
// Both staged via global_load_lds (linear dest, inverse-swizzled global source).
__global__ __launch_bounds__(256) void k_attn(const unsigned short* __restrict__ qkv,
                                              const unsigned short* __restrict__ ktg,
                                              unsigned short* __restrict__ outb) {
    __shared__ unsigned short kbuf[2][4096];
    __shared__ unsigned short vbuf[2][4096];
    int t = threadIdx.x;
    int l = t & 63, l15 = l & 15, lg = l >> 4, w = t >> 6;
    int h = blockIdx.y, qt = blockIdx.x;
    int n = qt * 64 + w * 16 + l15;

    const unsigned short* qb = qkv + (size_t)(h * 64) * 4096;
    const unsigned short* vb = qkv + (size_t)(1024 + h * 64) * 4096;
    const unsigned short* kg = ktg + (size_t)h * 4096 * 64;

    // Q fragments (B-operand), loaded once from global (L2-hot)
    short8v qf[2];
#pragma unroll
    for (int s = 0; s < 2; s++) {
        short8v v;
#pragma unroll
        for (int j = 0; j < 8; j++) {
            int d = s * 32 + ((j < 4) ? (4 * lg + j) : (16 + 4 * lg + (j - 4)));
            v[j] = (short)qb[(size_t)d * 4096 + n];
        }
        qf[s] = v;
    }

    f32x4 od[4] = {};
    float mrun = 0.f, lrun = 0.f;
    const float LOG2E = 1.44269504f;

    int lg1 = lg >> 1, lg8 = 8 * (lg & 1), m7 = l15 & 7;

#define STAGE(kt, b)                                                                   \
    {                                                                                  \
        _Pragma("unroll") for (int i = 0; i < 2; i++) {                                \
            int u = t + 256 * i;                                                       \
            int row = u >> 3;                                                          \
            int ck = (u & 7) ^ (row & 7);                                              \
            gload16(kg + ((size_t)((kt) * 64 + row) << 6) + ck * 8, &kbuf[b][u * 8]);  \
            gload16(vb + ((size_t)row << 12) + (kt) * 64 + ck * 8, &vbuf[b][u * 8]);   \
        }                                                                              \
    }

    STAGE(0, 0);
    __syncthreads();

    int b = 0;
    for (int kt = 0; kt < 64; kt++) {
        if (kt < 63) STAGE(kt + 1, b ^ 1);

        const char* kl = (const char*)&kbuf[b][0];
        const char* vl = (const char*)&vbuf[b][0];

        // S^T[m][n] = sum_d K^T[m][d] Q[d][n]
        f32x4 st[4];
        __builtin_amdgcn_s_setprio(1);
#pragma unroll
        for (int mf = 0; mf < 4; mf++) {
            int m = 16 * mf + l15;
            short4v a0 = *(const short4v*)(kl + m * 128 + (((0 + lg1) ^ m7) << 4) + lg8);
            short4v a1 = *(const short4v*)(kl + m * 128 + (((2 + lg1) ^ m7) << 4) + lg8);
            short4v a2 = *(const short4v*)(kl + m * 128 + (((4 + lg1) ^ m7) << 4) + lg8);
            short4v a3 = *(const short4v*)(kl + m * 128 + (((6 + lg1) ^ m7) << 4) + lg8);
            short8v A0 = __builtin_shufflevector(a0, a1, 0, 1, 2, 3, 4, 5, 6, 7);
            short8v A1 = __builtin_shufflevector(a2, a3, 0, 1, 2, 3, 4, 5, 6, 7);
            f32x4 z = {};
            z = MFMA16(A0, qf[0], z);
            z = MFMA16(A1, qf[1], z);
            st[mf] = z;
        }
        __builtin_amdgcn_s_setprio(0);

        // online softmax with defer-max (THR=8)
        float pm = st[0][0];
#pragma unroll
        for (int mf = 0; mf < 4; mf++)
#pragma unroll
            for (int r = 0; r < 4; r++) pm = fmaxf(pm, st[mf][r]);
        pm = fmaxf(pm, __shfl_xor(pm, 16, 64));
        pm = fmaxf(pm, __shfl_xor(pm, 32, 64));
        if (!__all(pm <= mrun + 8.f)) {
            float mnew = fmaxf(mrun, pm);
            float alpha = __expf(mrun - mnew);
#pragma unroll
            for (int dg = 0; dg < 4; dg++)
#pragma unroll
                for (int r = 0; r < 4; r++) od[dg][r] *= alpha;
            lrun *= alpha;
            mrun = mnew;
        }
        float mc = mrun * LOG2E;
        float p[4][4];
        float ps = 0.f;
#pragma unroll
        for (int mf = 0; mf < 4; mf++)
#pragma unroll
            for (int r = 0; r < 4; r++) {
                float e = __builtin_amdgcn_exp2f(fmaf(st[mf][r], LOG2E, -mc));
                p[mf][r] = e;
                ps += e;
            }
        ps += __shfl_xor(ps, 16, 64);
        ps += __shfl_xor(ps, 32, 64);
        lrun += ps;

        // pack P^T -> bf16 B-operand (truncation via v_perm)
        u32x4 P0, P1;
#pragma unroll
        for (int q = 0; q < 2; q++) {
            P0[2 * q + 0] = __builtin_amdgcn_perm(__builtin_bit_cast(unsigned int, p[q][1]),
                                                  __builtin_bit_cast(unsigned int, p[q][0]), 0x07060302u);
            P0[2 * q + 1] = __builtin_amdgcn_perm(__builtin_bit_cast(unsigned int, p[q][3]),
                                                  __builtin_bit_cast(unsigned int, p[q][2]), 0x07060302u);
            P1[2 * q + 0] = __builtin_amdgcn_perm(__builtin_bit_cast(unsigned int, p[2 + q][1]),
                                                  __builtin_bit_cast(unsigned int, p[2 + q][0]), 0x07060302u);
            P1[2 * q + 1] = __builtin_amdgcn_perm(__builtin_bit_cast(unsigned int, p[2 + q][3]),
                                                  __builtin_bit_cast(unsigned int, p[2 + q][2]), 0x07060302u);
        }
        short8v pb0 = __builtin_bit_cast(short8v, P0);
        short8v pb1 = __builtin_bit_cast(short8v, P1);

        // O^T[d][n] += V[d][m] P^T[m][n]
        __builtin_amdgcn_s_setprio(1);
#pragma unroll
        for (int dg = 0; dg < 4; dg++) {
            int d = 16 * dg + l15;
            short4v a0 = *(const short4v*)(vl + d * 128 + (((0 + lg1) ^ m7) << 4) + lg8);
            short4v a1 = *(const short4v*)(vl + d * 128 + (((2 + lg1) ^ m7) << 4) + lg8);
            short4v a2 = *(const short4v*)(vl + d * 128 + (((4 + lg1) ^ m7) << 4) + lg8);
            short4v a3 = *(const short4v*)(vl + d * 128 + (((6 + lg1) ^ m7) << 4) + lg8);
            short8v A0 = __builtin_shufflevector(a0, a1, 0, 1, 2, 3, 4, 5, 6, 7);
            short8v A1 = __builtin_shufflevector(a2, a3, 0, 1, 2, 3, 4, 5, 6, 7);
            od[dg] = MFMA16(A0, pb0, od[dg]);
            od[dg] = MFMA16(A1, pb1, od[dg]);
        }
        __builtin_amdgcn_s_setprio(0);

        __syncthreads();
        b ^= 1;
    }
#undef STAGE

    float inv = 1.0f / lrun;
#pragma unroll
    for (int dg = 0; dg < 4; dg++)
#pragma unroll
        for (int r = 0; r < 4; r++) {
            int d = 16 * dg + 4 * lg + r;
            outb[(size_t)(h * 64 + d) * 4096 + n] = bf16r(od[dg][r] * inv);
        }
}

// ---------------- bilinear upsample 64->256 + bias + residual (float4) ----------------
__global__ __launch_bounds__(256) void k_up(const float* __restrict__ x,
                                            const unsigned short* __restrict__ low,
                                            const float* __restrict__ proj_b,
                                            const float* __restrict__ gamma,
                                            float* __restrict__ out) {
    int t = threadIdx.x;
    int hs = t >> 6;
    int hh = blockIdx.x * 4 + hs;
    int c = blockIdx.y;
    int a = t & 63;

    int ph = hh & 3, Ah = hh >> 2;
    int y0 = Ah + ((ph < 2) ? -1 : 0);
    float fy = (ph < 2) ? (0.625f + 0.25f * ph) : (0.125f + 0.25f * (ph - 2));
    int y1 = min(y0 + 1, 63); y0 = max(y0, 0);

    const unsigned short* L0 = low + (size_t)c * 4096 + y0 * 64;
    const unsigned short* L1 = low + (size_t)c * 4096 + y1 * 64;
    int am = max(a - 1, 0), ap = min(a + 1, 63);
    float gy = 1.f - fy;
    float vm = gy * bff(L0[am]) + fy * bff(L1[am]);
    float v0 = gy * bff(L0[a])  + fy * bff(L1[a]);
    float vp = gy * bff(L0[ap]) + fy * bff(L1[ap]);

    float pb = proj_b[c], g = gamma[0];
    size_t idx = (size_t)c * 65536 + (size_t)hh * 256 + a * 4;
    float4 xi = *(const float4*)(x + idx);
    float4 o;
    o.x = xi.x + g * (0.375f * vm + 0.625f * v0 + pb);
    o.y = xi.y + g * (0.125f * vm + 0.875f * v0 + pb);
    o.z = xi.z + g * (0.875f * v0 + 0.125f * vp + pb);
    o.w = xi.w + g * (0.625f * v0 + 0.375f * vp + pb);
    *(float4*)(out + idx) = o;
}

extern "C" void kernel_launch(void* const* d_in, const int* in_sizes, int n_in,
                              void* d_out, int out_size, void* d_ws, size_t ws_size,
                              hipStream_t stream) {
    const float* x     = (const float*)d_in[0];
    const float* gnw   = (const float*)d_in[1];
    const float* gnb   = (const float*)d_in[2];
    const float* qkvw  = (const float*)d_in[3];
    const float* projw = (const float*)d_in[4];
    const float* projb = (const float*)d_in[5];
    const float* gamma = (const float*)d_in[6];
    const float* temp  = (const float*)d_in[7];

    char* ws = (char*)d_ws;
    const size_t MB = 1u << 20;
    float* gstats          = (float*)(ws + 0);
    float* partials        = (float*)(ws + 1024);
    float* xp              = (float*)(ws + 1 * MB);   // dead after k_xr
    unsigned short* ktg    = (unsigned short*)(ws + 4 * MB);  // reuses xp region (4MB)
    unsigned short* xr_b   = (unsigned short*)(ws + 9 * MB);
    unsigned short* wq_b   = (unsigned short*)(ws + 13 * MB);
    unsigned short* wp_b   = (unsigned short*)(ws + 15 * MB);
    unsigned short* qkv_b  = (unsigned short*)(ws + 16 * MB);
    unsigned short* attn_b = (unsigned short*)(ws + 28 * MB);
    unsigned short* low_b  = (unsigned short*)(ws + 32 * MB);
    float* out = (float*)d_out;

    k_wconv<<<4096, 256, 0, stream>>>(qkvw, projw, temp, wq_b, wp_b);
    k_pool<<<dim3(64, 512), 256, 0, stream>>>(x, xp, partials);
    k_stats<<<8, 256, 0, stream>>>(partials, gstats);
    k_xr<<<8192, 256, 0, stream>>>(xp, gstats, gnw, gnb, xr_b);
    k_gemm<<<dim3(32, 12), 256, 0, stream>>>(wq_b, xr_b, qkv_b);
    k_ktr<<<dim3(64, 8), 256, 0, stream>>>(qkv_b, ktg);
    k_attn<<<dim3(64, 8), 256, 0, stream>>>(qkv_b, ktg, attn_b);
    k_gemm<<<dim3(32, 4), 256, 0, stream>>>(wp_b, attn_b, low_b);
    k_up<<<dim3(64, 512), 256, 0, stream>>>(x, low_b, projb, gamma, out);
}

// Round 3
// 225.719 us; speedup vs baseline: 1.1564x; 1.0243x over previous
//
#include <hip/hip_runtime.h>
#include <hip/hip_bf16.h>

// Pipeline:
//  k_wconv : qkv_w/proj_w fp32 -> bf16 (q rows pre-scaled by temperature[h]/8)
//  k_pool  : x (512,256,256) -> pooled xp (512,64,64) fp32 + per-group partial stats
//  k_stats : reduce partials -> mean/rstd per group
//  k_xr    : xr = GN_affine(xp) + posenc -> bf16 (512,4096)
//  k_gemm  : qkv = Wq(1536,512) x xr(512,4096) -> bf16
//  k_ktr   : K section -> ktg (8,4096,64) for async staging
//  k_attn  : flash attn SPLIT-M (4 segments): partial O (f32, in d_out) + (m,l)
//  k_merge : combine 4 partials -> attn_b bf16
//  k_gemm  : low = Wp(512,512) x attn(512,4096) -> bf16
//  k_up    : out = x + gamma * (bilerp_4x(low) + proj_b)

typedef __attribute__((ext_vector_type(4))) short short4v;
typedef __attribute__((ext_vector_type(8))) short short8v;
typedef __attribute__((ext_vector_type(4))) float f32x4;
typedef __attribute__((ext_vector_type(4))) unsigned int u32x4;

#define MFMA16(a, b, c) __builtin_amdgcn_mfma_f32_16x16x32_bf16(a, b, c, 0, 0, 0)

__device__ __forceinline__ unsigned short bf16r(float f) {
    unsigned int u = __builtin_bit_cast(unsigned int, f);
    u += 0x7fffu + ((u >> 16) & 1u);
    return (unsigned short)(u >> 16);
}
__device__ __forceinline__ float bff(unsigned short s) {
    unsigned int u = ((unsigned int)s) << 16;
    return __builtin_bit_cast(float, u);
}

typedef const __attribute__((address_space(1))) unsigned int guint;
typedef __attribute__((address_space(3))) unsigned int luint;
__device__ __forceinline__ void gload16(const void* g, void* l) {
    __builtin_amdgcn_global_load_lds((guint*)g, (luint*)l, 16, 0, 0);
}

// ---------------- weight conversion ----------------
__global__ __launch_bounds__(256) void k_wconv(const float* __restrict__ qkv_w,
                                               const float* __restrict__ proj_w,
                                               const float* __restrict__ temp,
                                               unsigned short* __restrict__ wq_b,
                                               unsigned short* __restrict__ wp_b) {
    int idx = blockIdx.x * 256 + threadIdx.x;
    const int NQ = 1536 * 512;
    if (idx < NQ) {
        int o = idx >> 9;
        float sc = (o < 512) ? temp[o >> 6] * 0.125f : 1.0f;
        wq_b[idx] = bf16r(qkv_w[idx] * sc);
    } else {
        int j = idx - NQ;
        wp_b[j] = bf16r(proj_w[j]);
    }
}

// ---------------- pool + group partial stats ----------------
__global__ __launch_bounds__(256) void k_pool(const float* __restrict__ x,
                                              float* __restrict__ xp,
                                              float* __restrict__ partials) {
    int hr = blockIdx.x;
    int c  = blockIdx.y;
    int t = threadIdx.x;
    int r = t >> 6, wq = t & 63;
    const float4* src = (const float4*)(x + (size_t)c * 65536 + (size_t)(4 * hr + r) * 256 + 4 * wq);
    float4 v = *src;
    float s4 = v.x + v.y + v.z + v.w;
    float q4 = v.x * v.x + v.y * v.y + v.z * v.z + v.w * v.w;

    __shared__ float sm[256];
    __shared__ float wq4[4];
    sm[t] = s4;
    float qq = q4;
#pragma unroll
    for (int off = 1; off < 64; off <<= 1) qq += __shfl_xor(qq, off, 64);
    if ((t & 63) == 0) wq4[t >> 6] = qq;
    __syncthreads();
    if (t < 64) {
        float cs = sm[t] + sm[64 + t] + sm[128 + t] + sm[192 + t];
        xp[(size_t)c * 4096 + hr * 64 + t] = cs * (1.0f / 16.0f);
        float ts = cs;
#pragma unroll
        for (int off = 1; off < 64; off <<= 1) ts += __shfl_xor(ts, off, 64);
        if (t == 0) {
            int g = c >> 6;
            int slot = (c & 63) * 64 + hr;
            partials[(size_t)(g * 4096 + slot) * 2 + 0] = ts;
            partials[(size_t)(g * 4096 + slot) * 2 + 1] = wq4[0] + wq4[1] + wq4[2] + wq4[3];
        }
    }
}

// ---------------- group stats finalize ----------------
__global__ __launch_bounds__(256) void k_stats(const float* __restrict__ partials,
                                               float* __restrict__ gstats) {
    int g = blockIdx.x;
    int t = threadIdx.x;
    float s = 0.f, q = 0.f;
    for (int i = t; i < 4096; i += 256) {
        s += partials[(size_t)(g * 4096 + i) * 2 + 0];
        q += partials[(size_t)(g * 4096 + i) * 2 + 1];
    }
#pragma unroll
    for (int off = 1; off < 64; off <<= 1) {
        s += __shfl_xor(s, off, 64);
        q += __shfl_xor(q, off, 64);
    }
    __shared__ float ss[4], qs[4];
    if ((t & 63) == 0) { ss[t >> 6] = s; qs[t >> 6] = q; }
    __syncthreads();
    if (t == 0) {
        float S = ss[0] + ss[1] + ss[2] + ss[3];
        float Q = qs[0] + qs[1] + qs[2] + qs[3];
        const float inv = 1.0f / 4194304.0f;
        float m = S * inv;
        float var = Q * inv - m * m;
        gstats[2 * g] = m;
        gstats[2 * g + 1] = rsqrtf(var + 1e-5f);
    }
}

// ---------------- GN affine + positional encoding -> bf16 ----------------
__global__ __launch_bounds__(256) void k_xr(const float* __restrict__ xp,
                                            const float* __restrict__ gs,
                                            const float* __restrict__ gw,
                                            const float* __restrict__ gb,
                                            unsigned short* __restrict__ xr) {
    int idx = blockIdx.x * 256 + threadIdx.x;
    int c = idx >> 12, n = idx & 4095;
    int hr = n >> 6, wr = n & 63;
    int g = c >> 6;
    float m = gs[2 * g], rs = gs[2 * g + 1];
    float xn = (xp[idx] - m) * rs * gw[c] + gb[c];
    int i = c >> 2, kind = c & 3;
    float di = expf(-(float)i * 0.07195578415606394f);
    float arg = ((kind < 2) ? (float)hr : (float)wr) * di;
    float pe = 0.01f * ((kind & 1) ? cosf(arg) : sinf(arg));
    xr[idx] = bf16r(xn + pe);
}

// ---------------- bf16 GEMM: C[M,4096] = A[M,512] * B[512,4096] ----------------
__global__ __launch_bounds__(256) void k_gemm(const unsigned short* __restrict__ A,
                                              const unsigned short* __restrict__ B,
                                              unsigned short* __restrict__ C) {
    __shared__ unsigned short As[128][36];
    __shared__ unsigned short Bs[128][36];
    int t = threadIdx.x;
    int w = t >> 6, l = t & 63, l15 = l & 15, lg = l >> 4;
    int wrow = w >> 1, wcol = w & 1;
    int m0 = blockIdx.y * 128, n0 = blockIdx.x * 128;
    f32x4 acc[4][4] = {};

    for (int k0 = 0; k0 < 512; k0 += 32) {
#pragma unroll
        for (int i = 0; i < 4; i++) {
            int idx = t + 256 * i;
            int row = idx >> 3, kc = idx & 7;
            short4v av = *(const short4v*)(A + (size_t)(m0 + row) * 512 + k0 + 4 * kc);
            *(short4v*)&As[row][4 * kc] = av;
        }
#pragma unroll
        for (int i = 0; i < 4; i++) {
            int idx = t + 256 * i;
            int kr = idx >> 5, nc = idx & 31;
            short4v bv = *(const short4v*)(B + (size_t)(k0 + kr) * 4096 + n0 + 4 * nc);
#pragma unroll
            for (int j = 0; j < 4; j++) Bs[4 * nc + j][kr] = (unsigned short)bv[j];
        }
        __syncthreads();

        short8v af[4];
#pragma unroll
        for (int mi = 0; mi < 4; mi++) {
            int ar = wrow * 64 + mi * 16 + l15;
            short4v a0 = *(const short4v*)&As[ar][4 * lg];
            short4v a1 = *(const short4v*)&As[ar][16 + 4 * lg];
            af[mi] = __builtin_shufflevector(a0, a1, 0, 1, 2, 3, 4, 5, 6, 7);
        }
#pragma unroll
        for (int ni = 0; ni < 4; ni++) {
            int bc = wcol * 64 + ni * 16 + l15;
            short4v b0 = *(const short4v*)&Bs[bc][4 * lg];
            short4v b1 = *(const short4v*)&Bs[bc][16 + 4 * lg];
            short8v bf = __builtin_shufflevector(b0, b1, 0, 1, 2, 3, 4, 5, 6, 7);
#pragma unroll
            for (int mi = 0; mi < 4; mi++) acc[mi][ni] = MFMA16(af[mi], bf, acc[mi][ni]);
        }
        __syncthreads();
    }
#pragma unroll
    for (int mi = 0; mi < 4; mi++)
#pragma unroll
        for (int ni = 0; ni < 4; ni++) {
            int row = m0 + wrow * 64 + mi * 16 + 4 * lg;
            int col = n0 + wcol * 64 + ni * 16 + l15;
#pragma unroll
            for (int r = 0; r < 4; r++)
                C[(size_t)(row + r) * 4096 + col] = bf16r(acc[mi][ni][r]);
        }
}

// ---------------- K transpose: qkv K section -> ktg[h][m][d] ----------------
__global__ __launch_bounds__(256) void k_ktr(const unsigned short* __restrict__ qkv,
                                             unsigned short* __restrict__ ktg) {
    __shared__ unsigned short lt[64][72];
    int t = threadIdx.x;
    int mt = blockIdx.x;
    int h  = blockIdx.y;
    const unsigned short* kb = qkv + (size_t)(512 + h * 64) * 4096 + mt * 64;
    int d = t >> 2, seg = t & 3;
    short8v v0 = *(const short8v*)(kb + (size_t)d * 4096 + seg * 16);
    short8v v1 = *(const short8v*)(kb + (size_t)d * 4096 + seg * 16 + 8);
    *(short8v*)&lt[d][seg * 16] = v0;
    *(short8v*)&lt[d][seg * 16 + 8] = v1;
    __syncthreads();
    int m = t >> 2, ds = t & 3;
    unsigned short o[16];
#pragma unroll
    for (int j = 0; j < 16; j++) o[j] = lt[ds * 16 + j][m];
    unsigned short* dst = ktg + ((size_t)h * 4096 + (size_t)mt * 64 + m) * 64 + ds * 16;
    *(short8v*)dst = *(const short8v*)&o[0];
    *(short8v*)(dst + 8) = *(const short8v*)&o[8];
}

// ---------------- flash attention, split-m (4 segments) ----------------
// grid (64 qt, 8 h, 4 seg); each block: 16 k-tiles of 64.
// Outputs raw partial O^T (f32) + per-n (m, l).
__global__ __launch_bounds__(256) void k_attn(const unsigned short* __restrict__ qkv,
                                              const unsigned short* __restrict__ ktg,
                                              float* __restrict__ opart,
                                              float* __restrict__ ml) {
    __shared__ unsigned short kbuf[2][4096];
    __shared__ unsigned short vbuf[2][4096];
    int t = threadIdx.x;
    int l = t & 63, l15 = l & 15, lg = l >> 4, w = t >> 6;
    int h = blockIdx.y, qt = blockIdx.x, seg = blockIdx.z;
    int n = qt * 64 + w * 16 + l15;

    const unsigned short* qb = qkv + (size_t)(h * 64) * 4096;
    const unsigned short* vb = qkv + (size_t)(1024 + h * 64) * 4096;
    const unsigned short* kg = ktg + (size_t)h * 4096 * 64;

    // Q fragments (B-operand)
    short8v qf[2];
#pragma unroll
    for (int s = 0; s < 2; s++) {
        short8v v;
#pragma unroll
        for (int j = 0; j < 8; j++) {
            int d = s * 32 + ((j < 4) ? (4 * lg + j) : (16 + 4 * lg + (j - 4)));
            v[j] = (short)qb[(size_t)d * 4096 + n];
        }
        qf[s] = v;
    }

    // staging lane pointers (hoisted; per-tile += const)
    int u0 = t, u1 = t + 256;
    int r0 = u0 >> 3, c0 = ((u0 & 7) ^ (r0 & 7)) * 8;
    int r1 = u1 >> 3, c1 = ((u1 & 7) ^ (r1 & 7)) * 8;
    const unsigned short* kp0 = kg + (size_t)(seg * 1024 + r0) * 64 + c0;
    const unsigned short* kp1 = kg + (size_t)(seg * 1024 + r1) * 64 + c1;
    const unsigned short* vp0 = vb + (size_t)r0 * 4096 + seg * 1024 + c0;
    const unsigned short* vp1 = vb + (size_t)r1 * 4096 + seg * 1024 + c1;

    f32x4 od[4] = {};
    float mrun = 0.f, lrun = 0.f;
    const float LOG2E = 1.44269504f;

    int lg1 = lg >> 1, lg8 = 8 * (lg & 1), m7 = l15 & 7;

#define STAGE(i, b)                                           \
    {                                                         \
        gload16(kp0 + (i) * 4096, &kbuf[b][t * 8]);           \
        gload16(kp1 + (i) * 4096, &kbuf[b][t * 8 + 2048]);    \
        gload16(vp0 + (i) * 64, &vbuf[b][t * 8]);             \
        gload16(vp1 + (i) * 64, &vbuf[b][t * 8 + 2048]);      \
    }

    STAGE(0, 0);
    __syncthreads();

    int b = 0;
    for (int kt = 0; kt < 16; kt++) {
        if (kt < 15) STAGE(kt + 1, b ^ 1);

        const char* kl = (const char*)&kbuf[b][0];
        const char* vl = (const char*)&vbuf[b][0];

        f32x4 st[4];
        __builtin_amdgcn_s_setprio(1);
#pragma unroll
        for (int mf = 0; mf < 4; mf++) {
            int m = 16 * mf + l15;
            short4v a0 = *(const short4v*)(kl + m * 128 + (((0 + lg1) ^ m7) << 4) + lg8);
            short4v a1 = *(const short4v*)(kl + m * 128 + (((2 + lg1) ^ m7) << 4) + lg8);
            short4v a2 = *(const short4v*)(kl + m * 128 + (((4 + lg1) ^ m7) << 4) + lg8);
            short4v a3 = *(const short4v*)(kl + m * 128 + (((6 + lg1) ^ m7) << 4) + lg8);
            short8v A0 = __builtin_shufflevector(a0, a1, 0, 1, 2, 3, 4, 5, 6, 7);
            short8v A1 = __builtin_shufflevector(a2, a3, 0, 1, 2, 3, 4, 5, 6, 7);
            f32x4 z = {};
            z = MFMA16(A0, qf[0], z);
            z = MFMA16(A1, qf[1], z);
            st[mf] = z;
        }
        __builtin_amdgcn_s_setprio(0);

        // max via max3-friendly tree
        float pm;
        {
            float t0 = fmaxf(fmaxf(st[0][0], st[0][1]), st[0][2]);
            float t1 = fmaxf(fmaxf(st[0][3], st[1][0]), st[1][1]);
            float t2 = fmaxf(fmaxf(st[1][2], st[1][3]), st[2][0]);
            float t3 = fmaxf(fmaxf(st[2][1], st[2][2]), st[2][3]);
            float t4 = fmaxf(fmaxf(st[3][0], st[3][1]), st[3][2]);
            float t5 = fmaxf(fmaxf(t0, t1), st[3][3]);
            float t6 = fmaxf(fmaxf(t2, t3), t4);
            pm = fmaxf(t5, t6);
        }
        pm = fmaxf(pm, __shfl_xor(pm, 16, 64));
        pm = fmaxf(pm, __shfl_xor(pm, 32, 64));
        if (!__all(pm <= mrun + 8.f)) {
            float mnew = fmaxf(mrun, pm);
            float alpha = __expf(mrun - mnew);
#pragma unroll
            for (int dg = 0; dg < 4; dg++)
#pragma unroll
                for (int r = 0; r < 4; r++) od[dg][r] *= alpha;
            lrun *= alpha;
            mrun = mnew;
        }
        float mc = mrun * LOG2E;
        float p[4][4];
        float ps = 0.f;
#pragma unroll
        for (int mf = 0; mf < 4; mf++)
#pragma unroll
            for (int r = 0; r < 4; r++) {
                float e = __builtin_amdgcn_exp2f(fmaf(st[mf][r], LOG2E, -mc));
                p[mf][r] = e;
                ps += e;
            }
        ps += __shfl_xor(ps, 16, 64);
        ps += __shfl_xor(ps, 32, 64);
        lrun += ps;

        u32x4 P0, P1;
#pragma unroll
        for (int q = 0; q < 2; q++) {
            P0[2 * q + 0] = __builtin_amdgcn_perm(__builtin_bit_cast(unsigned int, p[q][1]),
                                                  __builtin_bit_cast(unsigned int, p[q][0]), 0x07060302u);
            P0[2 * q + 1] = __builtin_amdgcn_perm(__builtin_bit_cast(unsigned int, p[q][3]),
                                                  __builtin_bit_cast(unsigned int, p[q][2]), 0x07060302u);
            P1[2 * q + 0] = __builtin_amdgcn_perm(__builtin_bit_cast(unsigned int, p[2 + q][1]),
                                                  __builtin_bit_cast(unsigned int, p[2 + q][0]), 0x07060302u);
            P1[2 * q + 1] = __builtin_amdgcn_perm(__builtin_bit_cast(unsigned int, p[2 + q][3]),
                                                  __builtin_bit_cast(unsigned int, p[2 + q][2]), 0x07060302u);
        }
        short8v pb0 = __builtin_bit_cast(short8v, P0);
        short8v pb1 = __builtin_bit_cast(short8v, P1);

        __builtin_amdgcn_s_setprio(1);
#pragma unroll
        for (int dg = 0; dg < 4; dg++) {
            int d = 16 * dg + l15;
            short4v a0 = *(const short4v*)(vl + d * 128 + (((0 + lg1) ^ m7) << 4) + lg8);
            short4v a1 = *(const short4v*)(vl + d * 128 + (((2 + lg1) ^ m7) << 4) + lg8);
            short4v a2 = *(const short4v*)(vl + d * 128 + (((4 + lg1) ^ m7) << 4) + lg8);
            short4v a3 = *(const short4v*)(vl + d * 128 + (((6 + lg1) ^ m7) << 4) + lg8);
            short8v A0 = __builtin_shufflevector(a0, a1, 0, 1, 2, 3, 4, 5, 6, 7);
            short8v A1 = __builtin_shufflevector(a2, a3, 0, 1, 2, 3, 4, 5, 6, 7);
            od[dg] = MFMA16(A0, pb0, od[dg]);
            od[dg] = MFMA16(A1, pb1, od[dg]);
        }
        __builtin_amdgcn_s_setprio(0);

        __syncthreads();
        b ^= 1;
    }
#undef STAGE

    // write raw partials
    float* ob = opart + (size_t)seg * 2097152 + (size_t)(h * 64) * 4096 + n;
#pragma unroll
    for (int dg = 0; dg < 4; dg++)
#pragma unroll
        for (int r = 0; r < 4; r++) {
            int d = 16 * dg + 4 * lg + r;
            ob[(size_t)d * 4096] = od[dg][r];
        }
    if (lg == 0) {
        float* mlp = ml + (((size_t)seg * 8 + h) * 4096 + n) * 2;
        mlp[0] = mrun;
        mlp[1] = lrun;
    }
}

// ---------------- merge split-m partials -> attn bf16 ----------------
__global__ __launch_bounds__(256) void k_merge(const float* __restrict__ opart,
                                               const float* __restrict__ ml,
                                               unsigned short* __restrict__ attn_b) {
    int bid = blockIdx.x, t = threadIdx.x;
    int row = bid >> 2;                     // h*64 + d
    int n0 = (bid & 3) * 1024 + t * 4;
    int h = row >> 6;

    float m[4][4], lv[4][4];
#pragma unroll
    for (int s = 0; s < 4; s++) {
        const float2* mlp = (const float2*)(ml + (((size_t)s * 8 + h) * 4096 + n0) * 2);
#pragma unroll
        for (int j = 0; j < 4; j++) {
            float2 v = mlp[j];
            m[s][j] = v.x;
            lv[s][j] = v.y;
        }
    }
    f32x4 o[4];
#pragma unroll
    for (int s = 0; s < 4; s++)
        o[s] = *(const f32x4*)(opart + (size_t)s * 2097152 + (size_t)row * 4096 + n0);

    unsigned short res[4];
#pragma unroll
    for (int j = 0; j < 4; j++) {
        float M = fmaxf(fmaxf(m[0][j], m[1][j]), fmaxf(m[2][j], m[3][j]));
        float den = 0.f, num = 0.f;
#pragma unroll
        for (int s = 0; s < 4; s++) {
            float wgt = __expf(m[s][j] - M);
            den += wgt * lv[s][j];
            num += wgt * o[s][j];
        }
        res[j] = bf16r(num / den);
    }
    *(short4v*)(attn_b + (size_t)row * 4096 + n0) = *(const short4v*)res;
}

// ---------------- bilinear upsample 64->256 + bias + residual (float4) ----------------
__global__ __launch_bounds__(256) void k_up(const float* __restrict__ x,
                                            const unsigned short* __restrict__ low,
                                            const float* __restrict__ proj_b,
                                            const float* __restrict__ gamma,
                                            float* __restrict__ out) {
    int t = threadIdx.x;
    int hs = t >> 6;
    int hh = blockIdx.x * 4 + hs;
    int c = blockIdx.y;
    int a = t & 63;

    int ph = hh & 3, Ah = hh >> 2;
    int y0 = Ah + ((ph < 2) ? -1 : 0);
    float fy = (ph < 2) ? (0.625f + 0.25f * ph) : (0.125f + 0.25f * (ph - 2));
    int y1 = min(y0 + 1, 63); y0 = max(y0, 0);

    const unsigned short* L0 = low + (size_t)c * 4096 + y0 * 64;
    const unsigned short* L1 = low + (size_t)c * 4096 + y1 * 64;
    int am = max(a - 1, 0), ap = min(a + 1, 63);
    float gy = 1.f - fy;
    float vm = gy * bff(L0[am]) + fy * bff(L1[am]);
    float v0 = gy * bff(L0[a])  + fy * bff(L1[a]);
    float vp = gy * bff(L0[ap]) + fy * bff(L1[ap]);

    float pb = proj_b[c], g = gamma[0];
    size_t idx = (size_t)c * 65536 + (size_t)hh * 256 + a * 4;
    float4 xi = *(const float4*)(x + idx);
    float4 o;
    o.x = xi.x + g * (0.375f * vm + 0.625f * v0 + pb);
    o.y = xi.y + g * (0.125f * vm + 0.875f * v0 + pb);
    o.z = xi.z + g * (0.875f * v0 + 0.125f * vp + pb);
    o.w = xi.w + g * (0.625f * v0 + 0.375f * vp + pb);
    *(float4*)(out + idx) = o;
}

extern "C" void kernel_launch(void* const* d_in, const int* in_sizes, int n_in,
                              void* d_out, int out_size, void* d_ws, size_t ws_size,
                              hipStream_t stream) {
    const float* x     = (const float*)d_in[0];
    const float* gnw   = (const float*)d_in[1];
    const float* gnb   = (const float*)d_in[2];
    const float* qkvw  = (const float*)d_in[3];
    const float* projw = (const float*)d_in[4];
    const float* projb = (const float*)d_in[5];
    const float* gamma = (const float*)d_in[6];
    const float* temp  = (const float*)d_in[7];

    char* ws = (char*)d_ws;
    const size_t MB = 1u << 20;
    float* gstats          = (float*)(ws + 0);
    float* partials        = (float*)(ws + 1024);
    float* xp              = (float*)(ws + 1 * MB);            // dead after k_xr
    unsigned short* ktg    = (unsigned short*)(ws + 4 * MB);   // 4MB
    unsigned short* xr_b   = (unsigned short*)(ws + 9 * MB);   // dead after gemm1
    float* ml              = (float*)(ws + 9 * MB);            // reuses xr_b (1MB)
    unsigned short* wq_b   = (unsigned short*)(ws + 13 * MB);
    unsigned short* wp_b   = (unsigned short*)(ws + 15 * MB);
    unsigned short* qkv_b  = (unsigned short*)(ws + 16 * MB);
    unsigned short* attn_b = (unsigned short*)(ws + 28 * MB);
    unsigned short* low_b  = (unsigned short*)(ws + 32 * MB);
    float* out = (float*)d_out;
    float* opart = (float*)d_out;   // 32MB scratch; k_up overwrites later

    k_wconv<<<4096, 256, 0, stream>>>(qkvw, projw, temp, wq_b, wp_b);
    k_pool<<<dim3(64, 512), 256, 0, stream>>>(x, xp, partials);
    k_stats<<<8, 256, 0, stream>>>(partials, gstats);
    k_xr<<<8192, 256, 0, stream>>>(xp, gstats, gnw, gnb, xr_b);
    k_gemm<<<dim3(32, 12), 256, 0, stream>>>(wq_b, xr_b, qkv_b);
    k_ktr<<<dim3(64, 8), 256, 0, stream>>>(qkv_b, ktg);
    k_attn<<<dim3(64, 8, 4), 256, 0, stream>>>(qkv_b, ktg, opart, ml);
    k_merge<<<2048, 256, 0, stream>>>(opart, ml, attn_b);
    k_gemm<<<dim3(32, 4), 256, 0, stream>>>(wp_b, attn_b, low_b);
    k_up<<<dim3(64, 512), 256, 0, stream>>>(x, low_b, projb, gamma, out);
}